// Round 9
// baseline (314.334 us; speedup 1.0000x reference)
//
#include <hip/hip_runtime.h>
#include <cstdint>
#include <cstddef>

#define M_TOT 32768   // B*N
#define D_    256
#define DN_   128
#define TWO_D 512
#define H_    1024
#define TWO_H 2048

typedef unsigned short ushort_t;
typedef __attribute__((ext_vector_type(8))) short bf16x8;  // 8 bf16 = 4 VGPRs
typedef __attribute__((ext_vector_type(4))) float f32x4;

__device__ __forceinline__ ushort_t f2bf(float f) {
  union { float f; uint32_t i; } v; v.f = f;
  uint32_t r = v.i + 0x7fffu + ((v.i >> 16) & 1u);
  return (ushort_t)(r >> 16);
}

__device__ __forceinline__ void async_ld16(const void* g, void* l) {
  __builtin_amdgcn_global_load_lds(
      (const __attribute__((address_space(1))) void*)g,
      (__attribute__((address_space(3))) void*)l, 16, 0, 0);
}

// ---------------- fused prep: cond_ss + transpose(w_in) + transpose(w_out) + gather
// Sections by blockIdx.x: [0,16) cond, [16,144) w_in T, [144,208) w_out T, [208,336) gather.
__device__ __forceinline__ void transpose_body(
    const float* __restrict__ in, ushort_t* __restrict__ out, int R, int C,
    int bb, int tid, float* T) {
  int ctiles = C >> 6;
  int bi = bb / ctiles, bj = bb % ctiles;
  int r0 = bi * 64, c0 = bj * 64;
#pragma unroll
  for (int it = 0; it < 16; ++it) {
    int idx = it * 256 + tid;            // 0..4095
    int r = idx >> 6, c = idx & 63;
    T[r * 65 + c] = in[(size_t)(r0 + r) * C + c0 + c];
  }
  __syncthreads();
#pragma unroll
  for (int it = 0; it < 8; ++it) {
    int idx = it * 256 + tid;            // 0..2047
    int a = idx >> 5;                    // in-col -> out row
    int b = (idx & 31) * 2;              // in-row pair -> out col pair
    uint32_t pk = (uint32_t)f2bf(T[b * 65 + a]) |
                  ((uint32_t)f2bf(T[(b + 1) * 65 + a]) << 16);
    *(uint32_t*)&out[(size_t)(c0 + a) * R + r0 + b] = pk;
  }
}

__global__ __launch_bounds__(256) void prep_kernel(
    const float* __restrict__ ctx, const float* __restrict__ cond_w,
    const float* __restrict__ cond_b, float* __restrict__ ss,
    const float* __restrict__ w_in, ushort_t* __restrict__ WinT,
    const float* __restrict__ w_out, ushort_t* __restrict__ WoutT,
    const float* __restrict__ emb, const int* __restrict__ idx,
    ushort_t* __restrict__ W2T) {
  __shared__ float T[64 * 65];
  int bid = blockIdx.x, tid = threadIdx.x;
  if (bid < 16) {
    // cond_ss: ss[b][j] = ctx[b]·cond_w[:,j] + cond_b[j]
    int j = bid * 256 + tid;             // b = j>>9, col = j&511
    int b = j >> 9, col = j & 511;
    float acc = cond_b[col];
    for (int k = 0; k < DN_; ++k)
      acc += ctx[b * DN_ + k] * cond_w[k * TWO_D + col];
    ss[j] = acc;
  } else if (bid < 144) {
    transpose_body(w_in, WinT, D_, TWO_H, bid - 16, tid, T);
  } else if (bid < 208) {
    transpose_body(w_out, WoutT, H_, D_, bid - 144, tid, T);
  } else {
    // gather: W2T[f*8+o][d] = emb[idx[f]][d*8+o]
    int f = bid - 208;                   // 0..127
    bool looks64 = (idx[1] == 0) & (idx[3] == 0) & (idx[5] == 0) & (idx[7] == 0);
    int fi = looks64 ? idx[2 * f] : idx[f];
    const float* src = emb + (size_t)fi * 2048;
    int o = tid >> 5, d0 = (tid & 31) * 8;
    ushort_t buf[8];
#pragma unroll
    for (int k = 0; k < 8; ++k) buf[k] = f2bf(src[(d0 + k) * 8 + o]);
    *(bf16x8*)&W2T[(size_t)(f * 8 + o) * 256 + d0] = *(bf16x8*)buf;
  }
}

// ---------------- fused LayerNorm + FiLM  (one wave per row of 256), f32 in -> bf16 out
__global__ __launch_bounds__(256) void ln_film_kernel(
    const float* __restrict__ x, const float* __restrict__ ss,
    ushort_t* __restrict__ h) {
  int row = blockIdx.x * 4 + (threadIdx.x >> 6);
  int lane = threadIdx.x & 63;
  int b = row >> 12;
  const float* xr = x + (size_t)row * D_;
  float4 pk = *(const float4*)(xr + lane * 4);
  float f0 = pk.x, f1 = pk.y, f2 = pk.z, f3 = pk.w;
  float s = f0 + f1 + f2 + f3;
  float q = f0 * f0 + f1 * f1 + f2 * f2 + f3 * f3;
#pragma unroll
  for (int off = 32; off > 0; off >>= 1) {
    s += __shfl_xor(s, off, 64);
    q += __shfl_xor(q, off, 64);
  }
  float mean = s * (1.0f / 256.0f);
  float var = q * (1.0f / 256.0f) - mean * mean;
  float rs = rsqrtf(var + 1e-5f);
  int d = lane * 4;
  const float* ssb = ss + b * TWO_D;
  float o0 = (f0 - mean) * rs * (1.0f + ssb[d + 0]) + ssb[256 + d + 0];
  float o1 = (f1 - mean) * rs * (1.0f + ssb[d + 1]) + ssb[256 + d + 1];
  float o2 = (f2 - mean) * rs * (1.0f + ssb[d + 2]) + ssb[256 + d + 2];
  float o3 = (f3 - mean) * rs * (1.0f + ssb[d + 3]) + ssb[256 + d + 3];
  uint2 st;
  st.x = (uint32_t)f2bf(o0) | ((uint32_t)f2bf(o1) << 16);
  st.y = (uint32_t)f2bf(o2) | ((uint32_t)f2bf(o3) << 16);
  *(uint2*)(h + (size_t)row * D_ + lane * 4) = st;
}

// ---------------- fused gated-FFN: y = (gelu(h@Wu+bu)*(h@Wv+bv)) @ Wout + bout
// (proven R4 structure: 128-row blocks, 512 threads, 8 waves 4x2 grid, 32-row
// reg-resident A, 2 MFMAs per B-frag read, swizzled tiles, 6-phase ring,
// counted vmcnt(2) entries — 87-98 µs band, no spill)
__global__ __launch_bounds__(512, 2) void ffn_fused_kernel(
    const ushort_t* __restrict__ h,      // [32768][256] bf16
    const ushort_t* __restrict__ WinT,   // [2048][256] bf16 (u rows 0..1023, v 1024..2047)
    const float* __restrict__ bin,       // [2048] f32
    const ushort_t* __restrict__ WoutT,  // [256][1024] bf16
    const float* __restrict__ bout,      // [256] f32
    ushort_t* __restrict__ y) {          // [32768][256] bf16
  __shared__ ushort_t S3[3][8192];       // 3 x 16 KB staging ring
  __shared__ ushort_t Gs[128 * 72];      // 18.4 KB: g chunk, row-major stride 72
  __shared__ float Lbin[2048];           // 8 KB: bin biases
  const int tid = threadIdx.x, lane = tid & 63, wave = tid >> 6;  // wave 0..7
  const int wm = wave >> 1, wn = wave & 1;       // wm 0..3 row-quads
  const int r = lane >> 2, q = lane & 3;         // staging lane decomposition
  const int qs = q ^ ((r >> 1) & 3);             // swizzled source col-chunk
  const int l15 = lane & 15, l4 = lane >> 4;
  const int m0 = blockIdx.x * 128;
  // swizzled fragment offset inside a 16x32 tile (ushort units)
  const int fragoff = l15 * 32 + (l4 ^ ((l15 >> 1) & 3)) * 8;

  // per-thread staging bases (bytes)
  const char* winb  = (const char*)WinT  + r * 512 + qs * 16;
  const char* woutb = (const char*)WoutT + r * 2048 + qs * 16;

  // A fragments: this wave's 32 h-rows, all K=256, in registers (64 VGPR)
  const ushort_t* hp = h + (size_t)(m0 + wm * 32 + l15) * 256 + l4 * 8;
  bf16x8 a_reg[2][8];
#pragma unroll
  for (int rt = 0; rt < 2; ++rt)
#pragma unroll
    for (int kc = 0; kc < 8; ++kc)
      a_reg[rt][kc] = *(const bf16x8*)(hp + rt * 4096 + kc * 32);

  // bin -> LDS (one DMA per wave, pure-DMA keeps vmcnt counts exact)
  async_ld16((const char*)bin + wave * 1024 + lane * 16,
             (char*)Lbin + wave * 1024);

  auto stage_in = [&](ushort_t* dst, int jrow, int k0e) {
#pragma unroll
    for (int i = 0; i < 2; ++i) {
      int tt = i * 8 + wave;             // 0..15; <8 = u, >=8 = v
      int vv = tt >> 3, t7 = tt & 7;
      int ks = t7 >> 2, cc = t7 & 3;     // K-32 sub, gate-col-16 group
      async_ld16(winb + (size_t)vv * 524288 + jrow * 32768 + cc * 8192 +
                     k0e * 2 + ks * 64,
                 &dst[tt * 512]);
    }
  };
  auto stage_wout = [&](ushort_t* dst, int jrow, int s2) {
#pragma unroll
    for (int i = 0; i < 2; ++i) {
      int tt = i * 8 + wave;             // out-col tile nt
      async_ld16(woutb + (size_t)tt * 32768 + jrow * 128 + s2 * 64,
                 &dst[tt * 512]);
    }
  };

  // prologue: first two in-proj quarters of chunk 0
  stage_in(S3[0], 0, 0);
  stage_in(S3[1], 0, 64);

  f32x4 yac[2][8] = {};                  // rows rt*16, out-cols wn*128 + nt8*16

#define ENTRY2()                                        \
  asm volatile("s_waitcnt vmcnt(2)" ::: "memory");      \
  __builtin_amdgcn_s_barrier();                         \
  asm volatile("" ::: "memory");
#define ENTRY2L()                                                  \
  asm volatile("s_waitcnt vmcnt(2) lgkmcnt(0)" ::: "memory");      \
  __builtin_amdgcn_s_barrier();                                    \
  asm volatile("" ::: "memory");

#define MFMA_IN(buf, p_)                                                      \
  {                                                                           \
    const ushort_t* cur_ = (buf);                                             \
    __builtin_amdgcn_s_setprio(1);                                            \
    _Pragma("unroll")                                                         \
    for (int ks = 0; ks < 2; ++ks) {                                          \
      _Pragma("unroll")                                                       \
      for (int jj = 0; jj < 2; ++jj) {                                        \
        int tt = ks * 4 + wn * 2 + jj;                                        \
        bf16x8 bu = *(const bf16x8*)&cur_[tt * 512 + fragoff];                \
        bf16x8 bv = *(const bf16x8*)&cur_[(8 + tt) * 512 + fragoff];          \
        uac[0][jj] = __builtin_amdgcn_mfma_f32_16x16x32_bf16(a_reg[0][(p_)*2+ks], bu, uac[0][jj], 0, 0, 0); \
        uac[1][jj] = __builtin_amdgcn_mfma_f32_16x16x32_bf16(a_reg[1][(p_)*2+ks], bu, uac[1][jj], 0, 0, 0); \
        vac[0][jj] = __builtin_amdgcn_mfma_f32_16x16x32_bf16(a_reg[0][(p_)*2+ks], bv, vac[0][jj], 0, 0, 0); \
        vac[1][jj] = __builtin_amdgcn_mfma_f32_16x16x32_bf16(a_reg[1][(p_)*2+ks], bv, vac[1][jj], 0, 0, 0); \
      }                                                                       \
    }                                                                         \
    __builtin_amdgcn_s_setprio(0);                                            \
  }

#define MFMA_OUT(buf, s2_)                                                    \
  {                                                                           \
    const ushort_t* cur_ = (buf);                                             \
    bf16x8 gf0 = *(const bf16x8*)&Gs[(wm * 32 + l15) * 72 + (s2_) * 32 + l4 * 8];      \
    bf16x8 gf1 = *(const bf16x8*)&Gs[(wm * 32 + 16 + l15) * 72 + (s2_) * 32 + l4 * 8]; \
    __builtin_amdgcn_s_setprio(1);                                            \
    _Pragma("unroll")                                                         \
    for (int nt8 = 0; nt8 < 8; ++nt8) {                                       \
      bf16x8 bw = *(const bf16x8*)&cur_[(wn * 8 + nt8) * 512 + fragoff];      \
      yac[0][nt8] = __builtin_amdgcn_mfma_f32_16x16x32_bf16(gf0, bw, yac[0][nt8], 0, 0, 0); \
      yac[1][nt8] = __builtin_amdgcn_mfma_f32_16x16x32_bf16(gf1, bw, yac[1][nt8], 0, 0, 0); \
    }                                                                         \
    __builtin_amdgcn_s_setprio(0);                                            \
  }

  for (int j = 0; j < 16; ++j) {
    const int jn = (j + 1) & 15;         // wrap keeps vmcnt counts uniform
    f32x4 uac[2][2] = {}, vac[2][2] = {};

    ENTRY2(); stage_in(S3[2], j, 128);  MFMA_IN(S3[0], 0);   // p0
    ENTRY2(); stage_in(S3[0], j, 192);  MFMA_IN(S3[1], 1);   // p1
    ENTRY2(); stage_wout(S3[1], j, 0);  MFMA_IN(S3[2], 2);   // p2
    ENTRY2(); stage_wout(S3[2], j, 1);  MFMA_IN(S3[0], 3);   // p3

    // gelu-gate -> Gs (this wave's 32 rows x 32 gate-cols); flushed at p4 entry
#pragma unroll
    for (int jj = 0; jj < 2; ++jj) {
      int gcol = wn * 32 + jj * 16 + l15;
      float bub = Lbin[j * 64 + gcol];
      float bvb = Lbin[1024 + j * 64 + gcol];
#pragma unroll
      for (int rt = 0; rt < 2; ++rt) {
#pragma unroll
        for (int rr = 0; rr < 4; ++rr) {
          float u = uac[rt][jj][rr] + bub;
          float v = vac[rt][jj][rr] + bvb;
          float t = 0.7978845608028654f * (u + 0.044715f * u * u * u);
          float e = __expf(2.0f * t);
          float th = 1.0f - 2.0f / (e + 1.0f);
          float gl = 0.5f * u * (1.0f + th);
          Gs[(wm * 32 + rt * 16 + l4 * 4 + rr) * 72 + gcol] = f2bf(gl * v);
        }
      }
    }

    ENTRY2L(); stage_in(S3[0], jn, 0);  MFMA_OUT(S3[1], 0);  // p4
    ENTRY2();  stage_in(S3[1], jn, 64); MFMA_OUT(S3[2], 1);  // p5
  }

  // epilogue: y + bout -> bf16 via E (stride 264), two 64-row halves
  asm volatile("s_waitcnt vmcnt(0)" ::: "memory");
  __builtin_amdgcn_s_barrier();
  asm volatile("" ::: "memory");
  ushort_t* E = &S3[0][0];               // 64 x 264 x 2B = 33.8 KB (spans ring)
#pragma unroll
  for (int hh = 0; hh < 2; ++hh) {
    if ((wm >> 1) == hh) {
      int er0 = (wm & 1) * 32;
#pragma unroll
      for (int nt8 = 0; nt8 < 8; ++nt8) {
        int col = wn * 128 + nt8 * 16 + l15;
        float bb = bout[col];
#pragma unroll
        for (int rt = 0; rt < 2; ++rt)
#pragma unroll
          for (int rr = 0; rr < 4; ++rr)
            E[(er0 + rt * 16 + l4 * 4 + rr) * 264 + col] = f2bf(yac[rt][nt8][rr] + bb);
      }
    }
    asm volatile("s_waitcnt lgkmcnt(0)" ::: "memory");
    __builtin_amdgcn_s_barrier();
    asm volatile("" ::: "memory");
#pragma unroll
    for (int it = 0; it < 4; ++it) {
      int id = it * 512 + tid;           // 0..2047: rr = row, cc = 8-col chunk
      int rr = id >> 5, cc = id & 31;
      bf16x8 vv = *(const bf16x8*)&E[rr * 264 + cc * 8];
      *(bf16x8*)&y[(size_t)(m0 + hh * 64 + rr) * 256 + cc * 8] = vv;
    }
    if (hh == 0) {
      __builtin_amdgcn_s_barrier();      // readers done before E is rewritten
      asm volatile("" ::: "memory");
    }
  }
#undef ENTRY2
#undef ENTRY2L
#undef MFMA_IN
#undef MFMA_OUT
}

// ---------------- out GEMM: out[M][1024] = y[M][256] @ W2T[1024][256]^T, f32 out
// Reg-direct K-loop (no LDS staging, no main-loop barriers): A (=y, 16.8 MB)
// is L3-resident (just written by ffn); B (0.5 MB) is L2-resident and shared
// by consecutive blockIdx.x (same n0). Fragment mapping and MFMA order are
// bit-identical to the staged R8 version (the LDS swizzle round-tripped to
// identity). 4 blocks/CU (launch_bounds cap 128 VGPR) doubles TLP to hide
// L2/L3 latency. Coalesced Cs-roundtrip epilogue (33.8 KB) — R6's regression
// was its scatter-store epilogue, not the reg-direct loads.
__global__ __launch_bounds__(256, 4) void gemm_out_kernel(
    const ushort_t* __restrict__ A, const ushort_t* __restrict__ BT,
    float* __restrict__ C) {
  __shared__ float Cs[64 * 132];         // 33.8 KB epilogue staging
  const int tid = threadIdx.x, lane = tid & 63, wave = tid >> 6;
  const int wm = wave >> 1, wn = wave & 1;
  const int m0 = blockIdx.x * 128, n0 = blockIdx.y * 128;
  const int l15 = lane & 15, l4 = lane >> 4;
  const int N = 1024;
  const ushort_t* Ap = A + (size_t)(m0 + wm * 64 + l15) * 256 + l4 * 8;
  const ushort_t* Bp = BT + (size_t)(n0 + wn * 64 + l15) * 256 + l4 * 8;
  f32x4 acc[4][4] = {};
#pragma unroll
  for (int k0 = 0; k0 < 256; k0 += 64) {
#pragma unroll
    for (int ks = 0; ks < 2; ++ks) {
      bf16x8 a[4], b[4];
#pragma unroll
      for (int i = 0; i < 4; ++i)
        a[i] = *(const bf16x8*)(Ap + (size_t)i * 16 * 256 + k0 + ks * 32);
#pragma unroll
      for (int jt = 0; jt < 4; ++jt)
        b[jt] = *(const bf16x8*)(Bp + (size_t)jt * 16 * 256 + k0 + ks * 32);
#pragma unroll
      for (int i = 0; i < 4; ++i)
#pragma unroll
        for (int jt = 0; jt < 4; ++jt)
          acc[i][jt] = __builtin_amdgcn_mfma_f32_16x16x32_bf16(a[i], b[jt], acc[i][jt], 0, 0, 0);
    }
  }
  // coalesced epilogue via Cs, two 64-row passes
#pragma unroll
  for (int p = 0; p < 2; ++p) {
    __syncthreads();
    if (wm == p) {
#pragma unroll
      for (int jt = 0; jt < 4; ++jt) {
        int col = wn * 64 + jt * 16 + l15;
#pragma unroll
        for (int i = 0; i < 4; ++i) {
          int rl = i * 16 + (l4 << 2);
#pragma unroll
          for (int rr = 0; rr < 4; ++rr)
            Cs[(rl + rr) * 132 + col] = acc[i][jt][rr];
        }
      }
    }
    __syncthreads();
#pragma unroll
    for (int it = 0; it < 8; ++it) {
      int t = it * 256 + tid;            // 0..2047
      int rr = t >> 5, c = (t & 31) * 4; // row 0..63, col 0..124
      float4 v = *(const float4*)&Cs[rr * 132 + c];
      *(float4*)&C[(size_t)(m0 + p * 64 + rr) * N + n0 + c] = v;
    }
  }
}

extern "C" void kernel_launch(void* const* d_in, const int* in_sizes, int n_in,
                              void* d_out, int out_size, void* d_ws, size_t ws_size,
                              hipStream_t stream) {
  const float* x      = (const float*)d_in[0];
  const float* ctx    = (const float*)d_in[1];
  const int*   idx    = (const int*)d_in[2];
  const float* cond_w = (const float*)d_in[3];
  const float* cond_b = (const float*)d_in[4];
  const float* w_in   = (const float*)d_in[5];
  const float* b_in   = (const float*)d_in[6];
  const float* w_out  = (const float*)d_in[7];
  const float* b_out  = (const float*)d_in[8];
  const float* emb    = (const float*)d_in[9];

  char* w = (char*)d_ws;
  float* ss = (float*)w;           w += (size_t)8 * TWO_D * 4;        // 16 KB
  ushort_t* h = (ushort_t*)w;      w += (size_t)M_TOT * D_ * 2;       // 16.8 MB
  ushort_t* y = (ushort_t*)w;      w += (size_t)M_TOT * D_ * 2;       // 16.8 MB
  ushort_t* WinT = (ushort_t*)w;   w += (size_t)TWO_H * D_ * 2;       // 1 MB
  ushort_t* WoutT = (ushort_t*)w;  w += (size_t)D_ * H_ * 2;          // 0.5 MB
  ushort_t* W2T = (ushort_t*)w;    w += (size_t)H_ * D_ * 2;          // 0.5 MB

  prep_kernel<<<336, 256, 0, stream>>>(ctx, cond_w, cond_b, ss,
                                       w_in, WinT, w_out, WoutT, emb, idx, W2T);
  ln_film_kernel<<<M_TOT / 4, 256, 0, stream>>>(x, ss, h);
  ffn_fused_kernel<<<M_TOT / 128, 512, 0, stream>>>(h, WinT, b_in, WoutT, b_out, y);
  gemm_out_kernel<<<dim3(M_TOT / 128, H_ / 128), 256, 0, stream>>>(y, W2T, (float*)d_out);
}

// Round 11
// 279.392 us; speedup vs baseline: 1.1251x; 1.1251x over previous
//
#include <hip/hip_runtime.h>
#include <cstdint>
#include <cstddef>

#define M_TOT 32768   // B*N
#define D_    256
#define DN_   128
#define TWO_D 512
#define H_    1024
#define TWO_H 2048

typedef unsigned short ushort_t;
typedef __attribute__((ext_vector_type(8))) short bf16x8;  // 8 bf16 = 4 VGPRs
typedef __attribute__((ext_vector_type(4))) float f32x4;

__device__ __forceinline__ ushort_t f2bf(float f) {
  union { float f; uint32_t i; } v; v.f = f;
  uint32_t r = v.i + 0x7fffu + ((v.i >> 16) & 1u);
  return (ushort_t)(r >> 16);
}

__device__ __forceinline__ void async_ld16(const void* g, void* l) {
  __builtin_amdgcn_global_load_lds(
      (const __attribute__((address_space(1))) void*)g,
      (__attribute__((address_space(3))) void*)l, 16, 0, 0);
}

// ---------------- fused prep: cond_ss + transpose(w_in) + transpose(w_out) + gather
// Sections by blockIdx.x: [0,16) cond, [16,144) w_in T, [144,208) w_out T, [208,336) gather.
__device__ __forceinline__ void transpose_body(
    const float* __restrict__ in, ushort_t* __restrict__ out, int R, int C,
    int bb, int tid, float* T) {
  int ctiles = C >> 6;
  int bi = bb / ctiles, bj = bb % ctiles;
  int r0 = bi * 64, c0 = bj * 64;
#pragma unroll
  for (int it = 0; it < 16; ++it) {
    int idx = it * 256 + tid;            // 0..4095
    int r = idx >> 6, c = idx & 63;
    T[r * 65 + c] = in[(size_t)(r0 + r) * C + c0 + c];
  }
  __syncthreads();
#pragma unroll
  for (int it = 0; it < 8; ++it) {
    int idx = it * 256 + tid;            // 0..2047
    int a = idx >> 5;                    // in-col -> out row
    int b = (idx & 31) * 2;              // in-row pair -> out col pair
    uint32_t pk = (uint32_t)f2bf(T[b * 65 + a]) |
                  ((uint32_t)f2bf(T[(b + 1) * 65 + a]) << 16);
    *(uint32_t*)&out[(size_t)(c0 + a) * R + r0 + b] = pk;
  }
}

__global__ __launch_bounds__(256) void prep_kernel(
    const float* __restrict__ ctx, const float* __restrict__ cond_w,
    const float* __restrict__ cond_b, float* __restrict__ ss,
    const float* __restrict__ w_in, ushort_t* __restrict__ WinT,
    const float* __restrict__ w_out, ushort_t* __restrict__ WoutT,
    const float* __restrict__ emb, const int* __restrict__ idx,
    ushort_t* __restrict__ W2T) {
  __shared__ float T[64 * 65];
  int bid = blockIdx.x, tid = threadIdx.x;
  if (bid < 16) {
    // cond_ss: ss[b][j] = ctx[b]·cond_w[:,j] + cond_b[j]
    int j = bid * 256 + tid;             // b = j>>9, col = j&511
    int b = j >> 9, col = j & 511;
    float acc = cond_b[col];
    for (int k = 0; k < DN_; ++k)
      acc += ctx[b * DN_ + k] * cond_w[k * TWO_D + col];
    ss[j] = acc;
  } else if (bid < 144) {
    transpose_body(w_in, WinT, D_, TWO_H, bid - 16, tid, T);
  } else if (bid < 208) {
    transpose_body(w_out, WoutT, H_, D_, bid - 144, tid, T);
  } else {
    // gather: W2T[f*8+o][d] = emb[idx[f]][d*8+o]
    int f = bid - 208;                   // 0..127
    bool looks64 = (idx[1] == 0) & (idx[3] == 0) & (idx[5] == 0) & (idx[7] == 0);
    int fi = looks64 ? idx[2 * f] : idx[f];
    const float* src = emb + (size_t)fi * 2048;
    int o = tid >> 5, d0 = (tid & 31) * 8;
    ushort_t buf[8];
#pragma unroll
    for (int k = 0; k < 8; ++k) buf[k] = f2bf(src[(d0 + k) * 8 + o]);
    *(bf16x8*)&W2T[(size_t)(f * 8 + o) * 256 + d0] = *(bf16x8*)buf;
  }
}

// ---------------- fused LayerNorm + FiLM  (one wave per row of 256), f32 in -> bf16 out
__global__ __launch_bounds__(256) void ln_film_kernel(
    const float* __restrict__ x, const float* __restrict__ ss,
    ushort_t* __restrict__ h) {
  int row = blockIdx.x * 4 + (threadIdx.x >> 6);
  int lane = threadIdx.x & 63;
  int b = row >> 12;
  const float* xr = x + (size_t)row * D_;
  float4 pk = *(const float4*)(xr + lane * 4);
  float f0 = pk.x, f1 = pk.y, f2 = pk.z, f3 = pk.w;
  float s = f0 + f1 + f2 + f3;
  float q = f0 * f0 + f1 * f1 + f2 * f2 + f3 * f3;
#pragma unroll
  for (int off = 32; off > 0; off >>= 1) {
    s += __shfl_xor(s, off, 64);
    q += __shfl_xor(q, off, 64);
  }
  float mean = s * (1.0f / 256.0f);
  float var = q * (1.0f / 256.0f) - mean * mean;
  float rs = rsqrtf(var + 1e-5f);
  int d = lane * 4;
  const float* ssb = ss + b * TWO_D;
  float o0 = (f0 - mean) * rs * (1.0f + ssb[d + 0]) + ssb[256 + d + 0];
  float o1 = (f1 - mean) * rs * (1.0f + ssb[d + 1]) + ssb[256 + d + 1];
  float o2 = (f2 - mean) * rs * (1.0f + ssb[d + 2]) + ssb[256 + d + 2];
  float o3 = (f3 - mean) * rs * (1.0f + ssb[d + 3]) + ssb[256 + d + 3];
  uint2 st;
  st.x = (uint32_t)f2bf(o0) | ((uint32_t)f2bf(o1) << 16);
  st.y = (uint32_t)f2bf(o2) | ((uint32_t)f2bf(o3) << 16);
  *(uint2*)(h + (size_t)row * D_ + lane * 4) = st;
}

// ---------------- fused gated-FFN: y = (gelu(h@Wu+bu)*(h@Wv+bv)) @ Wout + bout
// (proven R4 structure: 128-row blocks, 512 threads, 8 waves 4x2 grid, 32-row
// reg-resident A, 2 MFMAs per B-frag read, swizzled tiles, 6-phase ring,
// counted vmcnt(2) entries — 87-98 µs band, no spill)
__global__ __launch_bounds__(512, 2) void ffn_fused_kernel(
    const ushort_t* __restrict__ h,      // [32768][256] bf16
    const ushort_t* __restrict__ WinT,   // [2048][256] bf16 (u rows 0..1023, v 1024..2047)
    const float* __restrict__ bin,       // [2048] f32
    const ushort_t* __restrict__ WoutT,  // [256][1024] bf16
    const float* __restrict__ bout,      // [256] f32
    ushort_t* __restrict__ y) {          // [32768][256] bf16
  __shared__ ushort_t S3[3][8192];       // 3 x 16 KB staging ring
  __shared__ ushort_t Gs[128 * 72];      // 18.4 KB: g chunk, row-major stride 72
  __shared__ float Lbin[2048];           // 8 KB: bin biases
  const int tid = threadIdx.x, lane = tid & 63, wave = tid >> 6;  // wave 0..7
  const int wm = wave >> 1, wn = wave & 1;       // wm 0..3 row-quads
  const int r = lane >> 2, q = lane & 3;         // staging lane decomposition
  const int qs = q ^ ((r >> 1) & 3);             // swizzled source col-chunk
  const int l15 = lane & 15, l4 = lane >> 4;
  const int m0 = blockIdx.x * 128;
  // swizzled fragment offset inside a 16x32 tile (ushort units)
  const int fragoff = l15 * 32 + (l4 ^ ((l15 >> 1) & 3)) * 8;

  // per-thread staging bases (bytes)
  const char* winb  = (const char*)WinT  + r * 512 + qs * 16;
  const char* woutb = (const char*)WoutT + r * 2048 + qs * 16;

  // A fragments: this wave's 32 h-rows, all K=256, in registers (64 VGPR)
  const ushort_t* hp = h + (size_t)(m0 + wm * 32 + l15) * 256 + l4 * 8;
  bf16x8 a_reg[2][8];
#pragma unroll
  for (int rt = 0; rt < 2; ++rt)
#pragma unroll
    for (int kc = 0; kc < 8; ++kc)
      a_reg[rt][kc] = *(const bf16x8*)(hp + rt * 4096 + kc * 32);

  // bin -> LDS (one DMA per wave, pure-DMA keeps vmcnt counts exact)
  async_ld16((const char*)bin + wave * 1024 + lane * 16,
             (char*)Lbin + wave * 1024);

  auto stage_in = [&](ushort_t* dst, int jrow, int k0e) {
#pragma unroll
    for (int i = 0; i < 2; ++i) {
      int tt = i * 8 + wave;             // 0..15; <8 = u, >=8 = v
      int vv = tt >> 3, t7 = tt & 7;
      int ks = t7 >> 2, cc = t7 & 3;     // K-32 sub, gate-col-16 group
      async_ld16(winb + (size_t)vv * 524288 + jrow * 32768 + cc * 8192 +
                     k0e * 2 + ks * 64,
                 &dst[tt * 512]);
    }
  };
  auto stage_wout = [&](ushort_t* dst, int jrow, int s2) {
#pragma unroll
    for (int i = 0; i < 2; ++i) {
      int tt = i * 8 + wave;             // out-col tile nt
      async_ld16(woutb + (size_t)tt * 32768 + jrow * 128 + s2 * 64,
                 &dst[tt * 512]);
    }
  };

  // prologue: first two in-proj quarters of chunk 0
  stage_in(S3[0], 0, 0);
  stage_in(S3[1], 0, 64);

  f32x4 yac[2][8] = {};                  // rows rt*16, out-cols wn*128 + nt8*16

#define ENTRY2()                                        \
  asm volatile("s_waitcnt vmcnt(2)" ::: "memory");      \
  __builtin_amdgcn_s_barrier();                         \
  asm volatile("" ::: "memory");
#define ENTRY2L()                                                  \
  asm volatile("s_waitcnt vmcnt(2) lgkmcnt(0)" ::: "memory");      \
  __builtin_amdgcn_s_barrier();                                    \
  asm volatile("" ::: "memory");

#define MFMA_IN(buf, p_)                                                      \
  {                                                                           \
    const ushort_t* cur_ = (buf);                                             \
    __builtin_amdgcn_s_setprio(1);                                            \
    _Pragma("unroll")                                                         \
    for (int ks = 0; ks < 2; ++ks) {                                          \
      _Pragma("unroll")                                                       \
      for (int jj = 0; jj < 2; ++jj) {                                        \
        int tt = ks * 4 + wn * 2 + jj;                                        \
        bf16x8 bu = *(const bf16x8*)&cur_[tt * 512 + fragoff];                \
        bf16x8 bv = *(const bf16x8*)&cur_[(8 + tt) * 512 + fragoff];          \
        uac[0][jj] = __builtin_amdgcn_mfma_f32_16x16x32_bf16(a_reg[0][(p_)*2+ks], bu, uac[0][jj], 0, 0, 0); \
        uac[1][jj] = __builtin_amdgcn_mfma_f32_16x16x32_bf16(a_reg[1][(p_)*2+ks], bu, uac[1][jj], 0, 0, 0); \
        vac[0][jj] = __builtin_amdgcn_mfma_f32_16x16x32_bf16(a_reg[0][(p_)*2+ks], bv, vac[0][jj], 0, 0, 0); \
        vac[1][jj] = __builtin_amdgcn_mfma_f32_16x16x32_bf16(a_reg[1][(p_)*2+ks], bv, vac[1][jj], 0, 0, 0); \
      }                                                                       \
    }                                                                         \
    __builtin_amdgcn_s_setprio(0);                                            \
  }

#define MFMA_OUT(buf, s2_)                                                    \
  {                                                                           \
    const ushort_t* cur_ = (buf);                                             \
    bf16x8 gf0 = *(const bf16x8*)&Gs[(wm * 32 + l15) * 72 + (s2_) * 32 + l4 * 8];      \
    bf16x8 gf1 = *(const bf16x8*)&Gs[(wm * 32 + 16 + l15) * 72 + (s2_) * 32 + l4 * 8]; \
    __builtin_amdgcn_s_setprio(1);                                            \
    _Pragma("unroll")                                                         \
    for (int nt8 = 0; nt8 < 8; ++nt8) {                                       \
      bf16x8 bw = *(const bf16x8*)&cur_[(wn * 8 + nt8) * 512 + fragoff];      \
      yac[0][nt8] = __builtin_amdgcn_mfma_f32_16x16x32_bf16(gf0, bw, yac[0][nt8], 0, 0, 0); \
      yac[1][nt8] = __builtin_amdgcn_mfma_f32_16x16x32_bf16(gf1, bw, yac[1][nt8], 0, 0, 0); \
    }                                                                         \
    __builtin_amdgcn_s_setprio(0);                                            \
  }

  for (int j = 0; j < 16; ++j) {
    const int jn = (j + 1) & 15;         // wrap keeps vmcnt counts uniform
    f32x4 uac[2][2] = {}, vac[2][2] = {};

    ENTRY2(); stage_in(S3[2], j, 128);  MFMA_IN(S3[0], 0);   // p0
    ENTRY2(); stage_in(S3[0], j, 192);  MFMA_IN(S3[1], 1);   // p1
    ENTRY2(); stage_wout(S3[1], j, 0);  MFMA_IN(S3[2], 2);   // p2
    ENTRY2(); stage_wout(S3[2], j, 1);  MFMA_IN(S3[0], 3);   // p3

    // gelu-gate -> Gs (this wave's 32 rows x 32 gate-cols); flushed at p4 entry
#pragma unroll
    for (int jj = 0; jj < 2; ++jj) {
      int gcol = wn * 32 + jj * 16 + l15;
      float bub = Lbin[j * 64 + gcol];
      float bvb = Lbin[1024 + j * 64 + gcol];
#pragma unroll
      for (int rt = 0; rt < 2; ++rt) {
#pragma unroll
        for (int rr = 0; rr < 4; ++rr) {
          float u = uac[rt][jj][rr] + bub;
          float v = vac[rt][jj][rr] + bvb;
          float t = 0.7978845608028654f * (u + 0.044715f * u * u * u);
          float e = __expf(2.0f * t);
          float th = 1.0f - 2.0f / (e + 1.0f);
          float gl = 0.5f * u * (1.0f + th);
          Gs[(wm * 32 + rt * 16 + l4 * 4 + rr) * 72 + gcol] = f2bf(gl * v);
        }
      }
    }

    ENTRY2L(); stage_in(S3[0], jn, 0);  MFMA_OUT(S3[1], 0);  // p4
    ENTRY2();  stage_in(S3[1], jn, 64); MFMA_OUT(S3[2], 1);  // p5
  }

  // epilogue: y + bout -> bf16 via E (stride 264), two 64-row halves
  asm volatile("s_waitcnt vmcnt(0)" ::: "memory");
  __builtin_amdgcn_s_barrier();
  asm volatile("" ::: "memory");
  ushort_t* E = &S3[0][0];               // 64 x 264 x 2B = 33.8 KB (spans ring)
#pragma unroll
  for (int hh = 0; hh < 2; ++hh) {
    if ((wm >> 1) == hh) {
      int er0 = (wm & 1) * 32;
#pragma unroll
      for (int nt8 = 0; nt8 < 8; ++nt8) {
        int col = wn * 128 + nt8 * 16 + l15;
        float bb = bout[col];
#pragma unroll
        for (int rt = 0; rt < 2; ++rt)
#pragma unroll
          for (int rr = 0; rr < 4; ++rr)
            E[(er0 + rt * 16 + l4 * 4 + rr) * 264 + col] = f2bf(yac[rt][nt8][rr] + bb);
      }
    }
    asm volatile("s_waitcnt lgkmcnt(0)" ::: "memory");
    __builtin_amdgcn_s_barrier();
    asm volatile("" ::: "memory");
#pragma unroll
    for (int it = 0; it < 4; ++it) {
      int id = it * 512 + tid;           // 0..2047: rr = row, cc = 8-col chunk
      int rr = id >> 5, cc = id & 31;
      bf16x8 vv = *(const bf16x8*)&E[rr * 264 + cc * 8];
      *(bf16x8*)&y[(size_t)(m0 + hh * 64 + rr) * 256 + cc * 8] = vv;
    }
    if (hh == 0) {
      __builtin_amdgcn_s_barrier();      // readers done before E is rewritten
      asm volatile("" ::: "memory");
    }
  }
#undef ENTRY2
#undef ENTRY2L
#undef MFMA_IN
#undef MFMA_OUT
}

// ---------------- out GEMM: out[M][1024] = y[M][256] @ W2T[1024][256]^T, f32 out
// B-persistent staged: block owns n-column (128 cols), stages the full-K B
// panel (64 KB) to LDS ONCE, then grid-strides 4 m-tiles of 256 rows with
// A-tile ping-pong (2 x 32 KB — 256 rows x 64 K x 2 B each; R10's 16 KB
// buffers overflowed -> corruption) and counted vmcnt(4) — R8's schedule and
// fragment mapping (bit-identical MFMA order). Staging DMA 262 -> 147 MB.
// 512 threads, 8 waves (wm row-quad of 64, wn col-half of 64); 128 KB LDS ->
// 1 block/CU = 2 waves/SIMD (same as ffn). Epilogue: 32-row Cs passes
// (16.9 KB) aliased onto the drained As[0].
__global__ __launch_bounds__(512, 2) void gemm_out_kernel(
    const ushort_t* __restrict__ A, const ushort_t* __restrict__ BT,
    float* __restrict__ C) {
  __shared__ ushort_t Bs[64 * 512];      // 64 KB: B panel, tile t = nt*8 + kc
  __shared__ ushort_t As[2][16384];      // 2 x 32 KB: A ping-pong, tile t = rt*2 + ks
  const int tid = threadIdx.x, lane = tid & 63, wave = tid >> 6;  // 0..7
  const int wm = wave >> 1, wn = wave & 1;   // row-quad (64 rows), col-half (64)
  const int n0 = blockIdx.y * 128;
  const int r = lane >> 2, q = lane & 3;
  const int qs = q ^ ((r >> 1) & 3);     // swizzled source col-chunk
  const int l15 = lane & 15, l4 = lane >> 4;
  const int fragoff = l15 * 32 + (l4 ^ ((l15 >> 1) & 3)) * 8;
  const int N = 1024, K = 256;

  // stage B panel once: 64 tiles of 16x32, 8 per wave (8 DMA/lane)
#pragma unroll
  for (int i = 0; i < 8; ++i) {
    int t = wave * 8 + i;                // nt = t>>3, kc = t&7
    int nt = t >> 3, kc = t & 7;
    async_ld16(BT + (size_t)(n0 + nt * 16 + r) * K + kc * 32 + qs * 8, &Bs[t * 512]);
  }
  auto stageA = [&](ushort_t* dst, int m0, int k0) {
#pragma unroll
    for (int i = 0; i < 4; ++i) {
      int t = i * 8 + wave;              // 0..31: rt = t>>1, ks = t&1
      int rt = t >> 1, ks = t & 1;
      async_ld16(A + (size_t)(m0 + rt * 16 + r) * K + k0 + ks * 32 + qs * 8,
                 &dst[t * 512]);
    }
  };

  for (int mt = 0; mt < 4; ++mt) {
    const int m0 = (blockIdx.x * 4 + mt) * 256;
    f32x4 acc[4][4] = {};
    stageA(As[0], m0, 0);                // 4 DMA/lane
#pragma unroll
    for (int k = 0; k < 4; ++k) {
      __builtin_amdgcn_s_barrier();      // prev readers done with target buffer
      asm volatile("" ::: "memory");
      if (k < 3) {
        stageA(As[(k + 1) & 1], m0, (k + 1) * 64);
        asm volatile("s_waitcnt vmcnt(4)" ::: "memory");  // cur landed, next in flight
      } else {
        asm volatile("s_waitcnt vmcnt(0)" ::: "memory");
      }
      __builtin_amdgcn_s_barrier();
      asm volatile("" ::: "memory");
      const ushort_t* curA = As[k & 1];
      __builtin_amdgcn_s_setprio(1);
#pragma unroll
      for (int ks = 0; ks < 2; ++ks) {
        int kc = k * 2 + ks;
        bf16x8 a[4], b[4];
#pragma unroll
        for (int i = 0; i < 4; ++i)
          a[i] = *(const bf16x8*)&curA[((wm * 4 + i) * 2 + ks) * 512 + fragoff];
#pragma unroll
        for (int jt = 0; jt < 4; ++jt)
          b[jt] = *(const bf16x8*)&Bs[((wn * 4 + jt) * 8 + kc) * 512 + fragoff];
#pragma unroll
        for (int i = 0; i < 4; ++i)
#pragma unroll
          for (int jt = 0; jt < 4; ++jt)
            acc[i][jt] = __builtin_amdgcn_mfma_f32_16x16x32_bf16(a[i], b[jt], acc[i][jt], 0, 0, 0);
      }
      __builtin_amdgcn_s_setprio(0);
    }
    // epilogue: 8 sub-passes of 32 rows via Cs (aliases As[0]; A fully drained)
    float* Cs = (float*)&As[0][0];       // 32 x 132 f32 = 16.9 KB (fits As[0])
#pragma unroll
    for (int p = 0; p < 4; ++p) {
#pragma unroll
      for (int hh = 0; hh < 2; ++hh) {
        __builtin_amdgcn_s_barrier();
        asm volatile("" ::: "memory");
        if (wm == p) {
#pragma unroll
          for (int ii = 0; ii < 2; ++ii) {
            int i = hh * 2 + ii;
#pragma unroll
            for (int jt = 0; jt < 4; ++jt) {
              int col = wn * 64 + jt * 16 + l15;
#pragma unroll
              for (int rr = 0; rr < 4; ++rr)
                Cs[(ii * 16 + (l4 << 2) + rr) * 132 + col] = acc[i][jt][rr];
            }
          }
        }
        asm volatile("s_waitcnt lgkmcnt(0)" ::: "memory");
        __builtin_amdgcn_s_barrier();
        asm volatile("" ::: "memory");
#pragma unroll
        for (int it = 0; it < 2; ++it) {
          int t = it * 512 + tid;        // 0..1023
          int rr = t >> 5, c = (t & 31) * 4;   // 32 rows x 128 cols
          float4 v = *(const float4*)&Cs[rr * 132 + c];
          *(float4*)&C[(size_t)(m0 + p * 64 + hh * 32 + rr) * N + n0 + c] = v;
        }
      }
    }
    __builtin_amdgcn_s_barrier();        // copies done before As is re-staged
    asm volatile("" ::: "memory");
  }
}

extern "C" void kernel_launch(void* const* d_in, const int* in_sizes, int n_in,
                              void* d_out, int out_size, void* d_ws, size_t ws_size,
                              hipStream_t stream) {
  const float* x      = (const float*)d_in[0];
  const float* ctx    = (const float*)d_in[1];
  const int*   idx    = (const int*)d_in[2];
  const float* cond_w = (const float*)d_in[3];
  const float* cond_b = (const float*)d_in[4];
  const float* w_in   = (const float*)d_in[5];
  const float* b_in   = (const float*)d_in[6];
  const float* w_out  = (const float*)d_in[7];
  const float* b_out  = (const float*)d_in[8];
  const float* emb    = (const float*)d_in[9];

  char* w = (char*)d_ws;
  float* ss = (float*)w;           w += (size_t)8 * TWO_D * 4;        // 16 KB
  ushort_t* h = (ushort_t*)w;      w += (size_t)M_TOT * D_ * 2;       // 16.8 MB
  ushort_t* y = (ushort_t*)w;      w += (size_t)M_TOT * D_ * 2;       // 16.8 MB
  ushort_t* WinT = (ushort_t*)w;   w += (size_t)TWO_H * D_ * 2;       // 1 MB
  ushort_t* WoutT = (ushort_t*)w;  w += (size_t)D_ * H_ * 2;          // 0.5 MB
  ushort_t* W2T = (ushort_t*)w;    w += (size_t)H_ * D_ * 2;          // 0.5 MB

  prep_kernel<<<336, 256, 0, stream>>>(ctx, cond_w, cond_b, ss,
                                       w_in, WinT, w_out, WoutT, emb, idx, W2T);
  ln_film_kernel<<<M_TOT / 4, 256, 0, stream>>>(x, ss, h);
  ffn_fused_kernel<<<M_TOT / 128, 512, 0, stream>>>(h, WinT, b_in, WoutT, b_out, y);
  gemm_out_kernel<<<dim3(32, 8), 512, 0, stream>>>(y, W2T, (float*)d_out);
}